// Round 7
// baseline (98.631 us; speedup 1.0000x reference)
//
#include <hip/hip_runtime.h>
#include <math.h>

// FSQ: x (64,32768,4) f32 -> z (level-major transposed layout) + code.
// LEVELS = [8,5,5,5], N rows of D=4.
#define N_ROWS 2097152  // 64*32768
#define NPT 4           // rows per thread (float4-coalesced stores need 4)

// Native Clang vector type (16B loads/stores).
typedef float floatx4 __attribute__((ext_vector_type(4)));

// Levels replicating np.linspace(-1,1,n,dtype=float32).
__device__ __constant__ float L8[8] = {
    -1.0f,
    (float)(1.0 * (2.0 / 7.0) - 1.0),
    (float)(2.0 * (2.0 / 7.0) - 1.0),
    (float)(3.0 * (2.0 / 7.0) - 1.0),
    (float)(4.0 * (2.0 / 7.0) - 1.0),
    (float)(5.0 * (2.0 / 7.0) - 1.0),
    (float)(6.0 * (2.0 / 7.0) - 1.0),
    1.0f};
__device__ __constant__ float L5[5] = {-1.0f, -0.5f, 0.0f, 0.5f, 1.0f};

// Exact slow-path quant: replicate np argmin |lv[j]-xi| (first-occurrence).
template <int NLEV>
__device__ inline void quant_exact(float xi, const float* __restrict__ lv,
                                   int& idx) {
    float best = fabsf(lv[0] - xi);
    int bi = 0;
#pragma unroll
    for (int j = 1; j < NLEV; ++j) {
        float d = fabsf(lv[j] - xi);
        if (d < best) { best = d; bi = j; }
    }
    idx = bi;
}

// Fast tanh: t = 1 - 2*rcp(exp2(x*2/ln2) + 1).
// v_exp_f32 (~1 ulp) + v_rcp_f32 (~1 ulp) -> abs output error <= ~1e-6.
__device__ __forceinline__ float fast_tanh(float x) {
    float e = __builtin_amdgcn_exp2f(x * 2.88539008177792681472f);  // 2/ln2
    return fmaf(-2.0f, __builtin_amdgcn_rcpf(e + 1.0f), 1.0f);
}

// Guard: |v - rint(v)| > 0.5 - EPS_U => too close to a decision boundary,
// take the exact path. EPS_U = 5e-5 units vs fast-path error <= 3.5e-6 units
// (14x margin), so off-guard indices are provably identical to the reference.
#define GTHR (0.5f - 5e-5f)

__global__ __launch_bounds__(256) void fsq_kernel(const float* __restrict__ x,
                                                  float* __restrict__ out) {
    const int t = blockIdx.x * blockDim.x + threadIdx.x;
    if (t >= N_ROWS / NPT) return;
    const long long n0 = (long long)t * NPT;

    floatx4 xin[NPT];
#pragma unroll
    for (int j = 0; j < NPT; ++j)
        xin[j] = reinterpret_cast<const floatx4*>(x)[n0 + j];

    float k0[NPT], k1[NPT], k2[NPT], k3[NPT];
    float m = 0.0f;  // max boundary proximity over all 16 values

#pragma unroll
    for (int j = 0; j < NPT; ++j) {
        const floatx4 xv = xin[j];
        float v0 = fmaf(fast_tanh(xv.x), 3.5f, 3.5f);
        float v1 = fmaf(fast_tanh(xv.y), 2.0f, 2.0f);
        float v2 = fmaf(fast_tanh(xv.z), 2.0f, 2.0f);
        float v3 = fmaf(fast_tanh(xv.w), 2.0f, 2.0f);
        k0[j] = rintf(v0);
        k1[j] = rintf(v1);
        k2[j] = rintf(v2);
        k3[j] = rintf(v3);
        m = fmaxf(m, fmaxf(fmaxf(fabsf(v0 - k0[j]), fabsf(v1 - k1[j])),
                           fmaxf(fabsf(v2 - k2[j]), fabsf(v3 - k3[j]))));
    }

    // Single per-thread branch: any of the 16 values near a boundary?
    if (m > GTHR) {
#pragma unroll
        for (int j = 0; j < NPT; ++j) {
            const floatx4 xv = xin[j];
            // Exact reference path: f64 tanh (rounds to numpy f32 tanh,
            // verified absmax 0.0 in R1) + exact argmin with f32 levels.
            float xi0 = (float)tanh((double)xv.x);
            float xi1 = (float)tanh((double)xv.y);
            float xi2 = (float)tanh((double)xv.z);
            float xi3 = (float)tanh((double)xv.w);
            int i0, i1, i2, i3;
            quant_exact<8>(xi0, L8, i0);
            quant_exact<5>(xi1, L5, i1);
            quant_exact<5>(xi2, L5, i2);
            quant_exact<5>(xi3, L5, i3);
            k0[j] = (float)i0; k1[j] = (float)i1;
            k2[j] = (float)i2; k3[j] = (float)i3;
        }
    }

    floatx4 z0v, z1v, z2v, z3v, cv;
#pragma unroll
    for (int j = 0; j < NPT; ++j) {
        // q values: dim0 bit-matches L8 via the same double formula it was
        // built from; dims 1-3 exact in f32. st = xi + (q - xi) == q here,
        // within 1 ulp of the reference's f32 st.
        z0v[j] = (float)((double)k0[j] * (2.0 / 7.0) - 1.0);
        z1v[j] = fmaf(k1[j], 0.5f, -1.0f);
        z2v[j] = fmaf(k2[j], 0.5f, -1.0f);
        z3v[j] = fmaf(k3[j], 0.5f, -1.0f);
        // code = i0 + 8*i1 + 40*i2 + 200*i3 (integers <= 999, exact in f32)
        cv[j] = fmaf(200.0f, k3[j], fmaf(40.0f, k2[j], fmaf(8.0f, k1[j], k0[j])));
    }

    // Regular cached stores: R6 showed nontemporal (`nt`) stores throttle to
    // ~950 GB/s on gfx950 (L2 bypass defeats write-combining). Keep L2 path.
    reinterpret_cast<floatx4*>(out + 0ll * N_ROWS)[t] = z0v;
    reinterpret_cast<floatx4*>(out + 1ll * N_ROWS)[t] = z1v;
    reinterpret_cast<floatx4*>(out + 2ll * N_ROWS)[t] = z2v;
    reinterpret_cast<floatx4*>(out + 3ll * N_ROWS)[t] = z3v;
    reinterpret_cast<floatx4*>(out + 4ll * N_ROWS)[t] = cv;
}

extern "C" void kernel_launch(void* const* d_in, const int* in_sizes, int n_in,
                              void* d_out, int out_size, void* d_ws, size_t ws_size,
                              hipStream_t stream) {
    const float* x = (const float*)d_in[0];
    float* out = (float*)d_out;
    const int threads = 256;
    const int total = N_ROWS / NPT;
    const int blocks = (total + threads - 1) / threads;
    fsq_kernel<<<blocks, threads, 0, stream>>>(x, out);
}

// Round 8
// 92.734 us; speedup vs baseline: 1.0636x; 1.0636x over previous
//
#include <hip/hip_runtime.h>
#include <math.h>

// FSQ: x (64,32768,4) f32 -> z (level-major transposed layout) + code.
// LEVELS = [8,5,5,5], N rows of D=4.
#define N_ROWS 2097152  // 64*32768
#define NPT 4           // rows per thread (float4-coalesced stores need 4)
#define MAXQ 32768      // worklist capacity ceiling (expected ~750 entries)

// Native Clang vector type (16B loads/stores).
typedef float floatx4 __attribute__((ext_vector_type(4)));

// Levels replicating np.linspace(-1,1,n,dtype=float32) (f64 math, f32 cast;
// verified bit-exact vs the np reference in R1: absmax 0.0).
__device__ __constant__ float L8[8] = {
    -1.0f,
    (float)(1.0 * (2.0 / 7.0) - 1.0),
    (float)(2.0 * (2.0 / 7.0) - 1.0),
    (float)(3.0 * (2.0 / 7.0) - 1.0),
    (float)(4.0 * (2.0 / 7.0) - 1.0),
    (float)(5.0 * (2.0 / 7.0) - 1.0),
    (float)(6.0 * (2.0 / 7.0) - 1.0),
    1.0f};
__device__ __constant__ float L5[5] = {-1.0f, -0.5f, 0.0f, 0.5f, 1.0f};

// Exact slow-path quant: replicate np argmin |lv[j]-xi| (first-occurrence).
template <int NLEV>
__device__ inline void quant_exact(float xi, const float* __restrict__ lv,
                                   int& idx) {
    float best = fabsf(lv[0] - xi);
    int bi = 0;
#pragma unroll
    for (int j = 1; j < NLEV; ++j) {
        float d = fabsf(lv[j] - xi);
        if (d < best) { best = d; bi = j; }
    }
    idx = bi;
}

// Exact reference path for one row: f64 tanh (rounds to numpy f32 tanh,
// verified absmax 0.0 in R1) + exact argmin with f32 levels.
__device__ inline void exact_row(const floatx4 xv, float& k0, float& k1,
                                 float& k2, float& k3) {
    float xi0 = (float)tanh((double)xv.x);
    float xi1 = (float)tanh((double)xv.y);
    float xi2 = (float)tanh((double)xv.z);
    float xi3 = (float)tanh((double)xv.w);
    int i0, i1, i2, i3;
    quant_exact<8>(xi0, L8, i0);
    quant_exact<5>(xi1, L5, i1);
    quant_exact<5>(xi2, L5, i2);
    quant_exact<5>(xi3, L5, i3);
    k0 = (float)i0; k1 = (float)i1; k2 = (float)i2; k3 = (float)i3;
}

// Fast tanh: t = 1 - 2*rcp(exp2(x*2/ln2) + 1).
// v_exp_f32 (~1 ulp) + v_rcp_f32 (~1 ulp) -> abs output error <= ~1e-6.
__device__ __forceinline__ float fast_tanh(float x) {
    float e = __builtin_amdgcn_exp2f(x * 2.88539008177792681472f);  // 2/ln2
    return fmaf(-2.0f, __builtin_amdgcn_rcpf(e + 1.0f), 1.0f);
}

// Guard: |v - rint(v)| > 0.5 - EPS_U => too close to a decision boundary.
// EPS_U = 5e-5 units vs fast-path error <= 3.5e-6 units (14x margin), so
// non-flagged rows are provably identical to the reference.
#define GTHR (0.5f - 5e-5f)

__global__ void zero_ctr(unsigned* __restrict__ wl) { wl[0] = 0; }

// Pass 1: uniform fast path. Boundary-suspect rows are appended to the
// worklist (tiny branch body -> no straggler-wave tail; R7's inline f64
// slow path produced 13% occupancy / 45 us from exactly that tail).
__global__ __launch_bounds__(256) void fsq_main(const float* __restrict__ x,
                                                float* __restrict__ out,
                                                unsigned* __restrict__ wl,
                                                unsigned cap) {
    const int t = blockIdx.x * blockDim.x + threadIdx.x;
    if (t >= N_ROWS / NPT) return;
    const long long n0 = (long long)t * NPT;

    floatx4 xin[NPT];
#pragma unroll
    for (int j = 0; j < NPT; ++j)
        xin[j] = reinterpret_cast<const floatx4*>(x)[n0 + j];

    float k0[NPT], k1[NPT], k2[NPT], k3[NPT];
    bool bad[NPT];

#pragma unroll
    for (int j = 0; j < NPT; ++j) {
        const floatx4 xv = xin[j];
        float v0 = fmaf(fast_tanh(xv.x), 3.5f, 3.5f);
        float v1 = fmaf(fast_tanh(xv.y), 2.0f, 2.0f);
        float v2 = fmaf(fast_tanh(xv.z), 2.0f, 2.0f);
        float v3 = fmaf(fast_tanh(xv.w), 2.0f, 2.0f);
        k0[j] = rintf(v0);
        k1[j] = rintf(v1);
        k2[j] = rintf(v2);
        k3[j] = rintf(v3);
        float m = fmaxf(fmaxf(fabsf(v0 - k0[j]), fabsf(v1 - k1[j])),
                        fmaxf(fabsf(v2 - k2[j]), fabsf(v3 - k3[j])));
        bad[j] = (m > GTHR);
    }

    // Defer suspect rows to pass 2 (expected ~750 of 2.1M rows total).
#pragma unroll
    for (int j = 0; j < NPT; ++j) {
        if (bad[j]) {
            if (cap != 0) {
                unsigned idx = atomicAdd(wl, 1u);
                if (idx < cap) {
                    wl[1 + idx] = (unsigned)(n0 + j);
                } else {
                    // worklist overflow (never with sane ws_size): inline exact
                    exact_row(xin[j], k0[j], k1[j], k2[j], k3[j]);
                }
            } else {
                exact_row(xin[j], k0[j], k1[j], k2[j], k3[j]);
            }
        }
    }

    floatx4 z0v, z1v, z2v, z3v, cv;
#pragma unroll
    for (int j = 0; j < NPT; ++j) {
        // dim0 bit-matches L8 via the same double formula it was built from;
        // dims 1-3 exact in f32. st = xi + (q - xi) == q here, within 1 ulp
        // of the reference's f32 st.
        z0v[j] = (float)((double)k0[j] * (2.0 / 7.0) - 1.0);
        z1v[j] = fmaf(k1[j], 0.5f, -1.0f);
        z2v[j] = fmaf(k2[j], 0.5f, -1.0f);
        z3v[j] = fmaf(k3[j], 0.5f, -1.0f);
        // code = i0 + 8*i1 + 40*i2 + 200*i3 (integers <= 999, exact in f32)
        cv[j] = fmaf(200.0f, k3[j], fmaf(40.0f, k2[j], fmaf(8.0f, k1[j], k0[j])));
    }

    reinterpret_cast<floatx4*>(out + 0ll * N_ROWS)[t] = z0v;
    reinterpret_cast<floatx4*>(out + 1ll * N_ROWS)[t] = z1v;
    reinterpret_cast<floatx4*>(out + 2ll * N_ROWS)[t] = z2v;
    reinterpret_cast<floatx4*>(out + 3ll * N_ROWS)[t] = z3v;
    reinterpret_cast<floatx4*>(out + 4ll * N_ROWS)[t] = cv;
}

// Pass 2: exact recompute of deferred rows (all concurrent -> no tail).
__global__ __launch_bounds__(256) void fsq_fix(const float* __restrict__ x,
                                               float* __restrict__ out,
                                               const unsigned* __restrict__ wl,
                                               unsigned cap) {
    unsigned cnt = wl[0];
    if (cnt > cap) cnt = cap;
    unsigned i = blockIdx.x * blockDim.x + threadIdx.x;
    if (i >= cnt) return;
    unsigned n = wl[1 + i];

    const floatx4 xv = reinterpret_cast<const floatx4*>(x)[n];
    float k0, k1, k2, k3;
    exact_row(xv, k0, k1, k2, k3);

    out[0ll * N_ROWS + n] = (float)((double)k0 * (2.0 / 7.0) - 1.0);
    out[1ll * N_ROWS + n] = fmaf(k1, 0.5f, -1.0f);
    out[2ll * N_ROWS + n] = fmaf(k2, 0.5f, -1.0f);
    out[3ll * N_ROWS + n] = fmaf(k3, 0.5f, -1.0f);
    out[4ll * N_ROWS + n] = fmaf(200.0f, k3, fmaf(40.0f, k2, fmaf(8.0f, k1, k0)));
}

extern "C" void kernel_launch(void* const* d_in, const int* in_sizes, int n_in,
                              void* d_out, int out_size, void* d_ws, size_t ws_size,
                              hipStream_t stream) {
    const float* x = (const float*)d_in[0];
    float* out = (float*)d_out;
    unsigned* wl = (unsigned*)d_ws;

    unsigned cap = 0;
    if (ws_size >= 8) {
        size_t c = ws_size / 4 - 1;
        cap = (unsigned)(c < (size_t)MAXQ ? c : (size_t)MAXQ);
    }

    const int threads = 256;
    const int total = N_ROWS / NPT;
    const int blocks = (total + threads - 1) / threads;

    if (cap != 0) zero_ctr<<<1, 1, 0, stream>>>(wl);
    fsq_main<<<blocks, threads, 0, stream>>>(x, out, wl, cap);
    if (cap != 0) {
        int fix_blocks = (int)((cap + threads - 1) / threads);
        fsq_fix<<<fix_blocks, threads, 0, stream>>>(x, out, wl, cap);
    }
}

// Round 9
// 86.117 us; speedup vs baseline: 1.1453x; 1.0768x over previous
//
#include <hip/hip_runtime.h>
#include <math.h>

// FSQ: x (64,32768,4) f32 -> z (level-major transposed layout) + code.
// LEVELS = [8,5,5,5], N rows of D=4.
#define N_ROWS 2097152  // 64*32768
#define NPT 4           // rows per thread (float4-coalesced stores need 4)
#define LQ 64           // per-block LDS worklist capacity (expect ~0.4 used)

// Native Clang vector type (16B loads/stores).
typedef float floatx4 __attribute__((ext_vector_type(4)));

// Levels replicating np.linspace(-1,1,n,dtype=float32) (f64 math, f32 cast;
// verified bit-exact vs the np reference in R1: absmax 0.0).
__device__ __constant__ float L8[8] = {
    -1.0f,
    (float)(1.0 * (2.0 / 7.0) - 1.0),
    (float)(2.0 * (2.0 / 7.0) - 1.0),
    (float)(3.0 * (2.0 / 7.0) - 1.0),
    (float)(4.0 * (2.0 / 7.0) - 1.0),
    (float)(5.0 * (2.0 / 7.0) - 1.0),
    (float)(6.0 * (2.0 / 7.0) - 1.0),
    1.0f};
__device__ __constant__ float L5[5] = {-1.0f, -0.5f, 0.0f, 0.5f, 1.0f};

// Exact slow-path quant: replicate np argmin |lv[j]-xi| (first-occurrence).
template <int NLEV>
__device__ inline void quant_exact(float xi, const float* __restrict__ lv,
                                   int& idx) {
    float best = fabsf(lv[0] - xi);
    int bi = 0;
#pragma unroll
    for (int j = 1; j < NLEV; ++j) {
        float d = fabsf(lv[j] - xi);
        if (d < best) { best = d; bi = j; }
    }
    idx = bi;
}

// Exact reference path for one row: f64 tanh (rounds to numpy f32 tanh,
// verified absmax 0.0 in R1) + exact argmin with f32 levels.
__device__ inline void exact_row(const floatx4 xv, float& k0, float& k1,
                                 float& k2, float& k3) {
    float xi0 = (float)tanh((double)xv.x);
    float xi1 = (float)tanh((double)xv.y);
    float xi2 = (float)tanh((double)xv.z);
    float xi3 = (float)tanh((double)xv.w);
    int i0, i1, i2, i3;
    quant_exact<8>(xi0, L8, i0);
    quant_exact<5>(xi1, L5, i1);
    quant_exact<5>(xi2, L5, i2);
    quant_exact<5>(xi3, L5, i3);
    k0 = (float)i0; k1 = (float)i1; k2 = (float)i2; k3 = (float)i3;
}

// Fast tanh: t = 1 - 2*rcp(exp2(x*2/ln2) + 1).
// v_exp_f32 (~1 ulp) + v_rcp_f32 (~1 ulp) -> abs output error <= ~1e-6.
__device__ __forceinline__ float fast_tanh(float x) {
    float e = __builtin_amdgcn_exp2f(x * 2.88539008177792681472f);  // 2/ln2
    return fmaf(-2.0f, __builtin_amdgcn_rcpf(e + 1.0f), 1.0f);
}

// Guard: |v - rint(v)| > 0.5 - EPS_U => too close to a decision boundary.
// EPS_U = 5e-5 units vs fast-path error <= 3.5e-6 units (14x margin), so
// non-flagged rows are provably identical to the reference.
#define GTHR (0.5f - 5e-5f)

// Single dispatch. Uniform fast path; boundary-suspect rows go to a
// per-block LDS worklist and are redone exactly after the barrier.
// (R7: inline slow path -> straggler-wave tail, 45 us, 13% occupancy.
//  R8: global 2-pass worklist -> tail gone but +2 dispatch overheads.)
__global__ __launch_bounds__(256) void fsq_kernel(const float* __restrict__ x,
                                                  float* __restrict__ out) {
    __shared__ unsigned s_cnt;
    __shared__ unsigned s_rows[LQ];

    if (threadIdx.x == 0) s_cnt = 0;
    __syncthreads();

    const int t = blockIdx.x * blockDim.x + threadIdx.x;  // grid divides exactly
    const long long n0 = (long long)t * NPT;

    floatx4 xin[NPT];
#pragma unroll
    for (int j = 0; j < NPT; ++j)
        xin[j] = reinterpret_cast<const floatx4*>(x)[n0 + j];

    float k0[NPT], k1[NPT], k2[NPT], k3[NPT];
    bool bad[NPT];

#pragma unroll
    for (int j = 0; j < NPT; ++j) {
        const floatx4 xv = xin[j];
        float v0 = fmaf(fast_tanh(xv.x), 3.5f, 3.5f);
        float v1 = fmaf(fast_tanh(xv.y), 2.0f, 2.0f);
        float v2 = fmaf(fast_tanh(xv.z), 2.0f, 2.0f);
        float v3 = fmaf(fast_tanh(xv.w), 2.0f, 2.0f);
        k0[j] = rintf(v0);
        k1[j] = rintf(v1);
        k2[j] = rintf(v2);
        k3[j] = rintf(v3);
        float m = fmaxf(fmaxf(fabsf(v0 - k0[j]), fabsf(v1 - k1[j])),
                        fmaxf(fabsf(v2 - k2[j]), fabsf(v3 - k3[j])));
        bad[j] = (m > GTHR);
    }

    // Enqueue suspect rows (expected 0.37/block; tiny branch body, no tail).
#pragma unroll
    for (int j = 0; j < NPT; ++j) {
        if (bad[j]) {
            unsigned s = atomicAdd(&s_cnt, 1u);
            if (s < LQ) {
                s_rows[s] = (unsigned)(n0 + j);
            } else {
                // overflow (probability ~0): inline exact fallback
                exact_row(xin[j], k0[j], k1[j], k2[j], k3[j]);
            }
        }
    }

    floatx4 z0v, z1v, z2v, z3v, cv;
#pragma unroll
    for (int j = 0; j < NPT; ++j) {
        // dim0 bit-matches L8 via the same double formula it was built from;
        // dims 1-3 exact in f32. st = xi + (q - xi) == q here, within 1 ulp
        // of the reference's f32 st.
        z0v[j] = (float)((double)k0[j] * (2.0 / 7.0) - 1.0);
        z1v[j] = fmaf(k1[j], 0.5f, -1.0f);
        z2v[j] = fmaf(k2[j], 0.5f, -1.0f);
        z3v[j] = fmaf(k3[j], 0.5f, -1.0f);
        // code = i0 + 8*i1 + 40*i2 + 200*i3 (integers <= 999, exact in f32)
        cv[j] = fmaf(200.0f, k3[j], fmaf(40.0f, k2[j], fmaf(8.0f, k1[j], k0[j])));
    }

    reinterpret_cast<floatx4*>(out + 0ll * N_ROWS)[t] = z0v;
    reinterpret_cast<floatx4*>(out + 1ll * N_ROWS)[t] = z1v;
    reinterpret_cast<floatx4*>(out + 2ll * N_ROWS)[t] = z2v;
    reinterpret_cast<floatx4*>(out + 3ll * N_ROWS)[t] = z3v;
    reinterpret_cast<floatx4*>(out + 4ll * N_ROWS)[t] = cv;

    // Block-local fixup. __syncthreads() drains the fast-path stores
    // (s_waitcnt vmcnt(0) before s_barrier), so the exact scalar stores
    // below are ordered after them in the same CU/L2 -> final value exact.
    __syncthreads();
    unsigned cnt = s_cnt;
    if (cnt > LQ) cnt = LQ;
    for (unsigned i = threadIdx.x; i < cnt; i += 256u) {
        unsigned n = s_rows[i];
        const floatx4 xv = reinterpret_cast<const floatx4*>(x)[n];  // L1/L2 hit
        float e0, e1, e2, e3;
        exact_row(xv, e0, e1, e2, e3);
        out[0ll * N_ROWS + n] = (float)((double)e0 * (2.0 / 7.0) - 1.0);
        out[1ll * N_ROWS + n] = fmaf(e1, 0.5f, -1.0f);
        out[2ll * N_ROWS + n] = fmaf(e2, 0.5f, -1.0f);
        out[3ll * N_ROWS + n] = fmaf(e3, 0.5f, -1.0f);
        out[4ll * N_ROWS + n] =
            fmaf(200.0f, e3, fmaf(40.0f, e2, fmaf(8.0f, e1, e0)));
    }
}

extern "C" void kernel_launch(void* const* d_in, const int* in_sizes, int n_in,
                              void* d_out, int out_size, void* d_ws, size_t ws_size,
                              hipStream_t stream) {
    const float* x = (const float*)d_in[0];
    float* out = (float*)d_out;
    const int threads = 256;
    const int total = N_ROWS / NPT;       // 524288, divides 256 exactly
    const int blocks = total / threads;   // 2048 (exact -> uniform barriers)
    fsq_kernel<<<blocks, threads, 0, stream>>>(x, out);
}